// Round 12
// baseline (420.752 us; speedup 1.0000x reference)
//
#include <hip/hip_runtime.h>

#define S_LEN 512
#define BSZ 8
#define NH 8
#define HD 64
#define IN_DIM 512
#define PROJ 2576   // NH*(5*HD+2)
#define SEG 322     // per-head: 5*64+2
#define AST 352     // act row stride f32: q64,k64,rk64,v64,rv64,beta,rbeta,pad -> 8 rows = 11*1024B
#define CHUNK 8
#define NCH 64      // 512/CHUNK
#define CB (CHUNK * AST * 4)  // 11264 bytes per chunk

typedef __attribute__((ext_vector_type(8))) __bf16 bf16x8;
typedef __attribute__((ext_vector_type(4))) float f32x4;

static __device__ __forceinline__ unsigned short f2bf(float f) {
  unsigned u = __float_as_uint(f);
  unsigned r = (u + 0x7fffu + ((u >> 16) & 1u)) >> 16;
  return (unsigned short)r;
}
static __device__ __forceinline__ float bf2f(unsigned short s) {
  return __uint_as_float(((unsigned)s) << 16);
}

static __device__ __forceinline__ void gl_lds16(const void* g, void* l) {
  __builtin_amdgcn_global_load_lds(
      (const __attribute__((address_space(1))) unsigned int*)g,
      (__attribute__((address_space(3))) unsigned int*)l, 16, 0, 0);
}

// ---------------- LayerNorm: x (4096x512 f32) -> normed bf16; also clears scan flags ----------------
__global__ __launch_bounds__(256) void ln_kernel(const float* __restrict__ x,
                                                 const float* __restrict__ gamma,
                                                 const float* __restrict__ beta,
                                                 unsigned short* __restrict__ out,
                                                 int* __restrict__ flags) {
  if (blockIdx.x == 0 && threadIdx.x < 64) flags[threadIdx.x] = 0;  // visible at kernel end
  int wave = threadIdx.x >> 6, lane = threadIdx.x & 63;
  int row = blockIdx.x * 4 + wave;
  const float* xr = x + (size_t)row * IN_DIM + lane * 8;
  float4 a = *(const float4*)xr;
  float4 b = *(const float4*)(xr + 4);
  float vals[8] = {a.x, a.y, a.z, a.w, b.x, b.y, b.z, b.w};
  float s = 0.f, ss = 0.f;
#pragma unroll
  for (int i = 0; i < 8; i++) { s += vals[i]; ss += vals[i] * vals[i]; }
#pragma unroll
  for (int o = 32; o; o >>= 1) { s += __shfl_xor(s, o); ss += __shfl_xor(ss, o); }
  float mu = s * (1.f / 512.f);
  float var = ss * (1.f / 512.f) - mu * mu;
  float rstd = rsqrtf(var + 1e-5f);
  const float* g = gamma + lane * 8;
  const float* be = beta + lane * 8;
  float4 g1 = *(const float4*)g, g2 = *(const float4*)(g + 4);
  float4 b1 = *(const float4*)be, b2 = *(const float4*)(be + 4);
  float gs[8] = {g1.x, g1.y, g1.z, g1.w, g2.x, g2.y, g2.z, g2.w};
  float bs[8] = {b1.x, b1.y, b1.z, b1.w, b2.x, b2.y, b2.z, b2.w};
  union { unsigned short u[8]; uint4 v; } pk;
#pragma unroll
  for (int i = 0; i < 8; i++) pk.u[i] = f2bf((vals[i] - mu) * rstd * gs[i] + bs[i]);
  *(uint4*)(out + (size_t)row * IN_DIM + lane * 8) = pk.v;
}

// ---------------- generic f32 -> bf16 cast ----------------
__global__ void cast_kernel(const float* __restrict__ in, unsigned short* __restrict__ out, int n) {
  int i = blockIdx.x * blockDim.x + threadIdx.x;
  int st = gridDim.x * blockDim.x;
  for (; i < n; i += st) out[i] = f2bf(in[i]);
}

// ---------------- GEMM 128x128 tile: C[m][n] = sum_k A[m][k]*B[n][k] ----------------
template <int BF16_OUT, int RESID>
__global__ __launch_bounds__(256) void gemm128(const unsigned short* __restrict__ A,
                                               const unsigned short* __restrict__ B,
                                               void* __restrict__ Cout,
                                               const float* __restrict__ resid,
                                               int M, int N, int K) {
  __shared__ __align__(16) unsigned short As[128 * 32];
  __shared__ __align__(16) unsigned short Bs[128 * 32];
  int tid = threadIdx.x;
  int lane = tid & 63, w = tid >> 6;
  int wr = w >> 1, wc = w & 1;
  int m0 = blockIdx.y * 128, n0 = blockIdx.x * 128;

  int r0 = (w * 2) * 16 + (lane >> 2);
  int r1 = (w * 2 + 1) * 16 + (lane >> 2);
  int kq = (lane & 3) * 8;
  const unsigned short* A0 = A + (size_t)(m0 + r0) * K + kq;
  const unsigned short* A1 = A + (size_t)(m0 + r1) * K + kq;
  int bn0 = n0 + r0; if (bn0 > N - 1) bn0 = N - 1;
  int bn1 = n0 + r1; if (bn1 > N - 1) bn1 = N - 1;
  const unsigned short* B0 = B + (size_t)bn0 * K + kq;
  const unsigned short* B1 = B + (size_t)bn1 * K + kq;
  char* asb0 = (char*)As + (w * 2) * 1024;
  char* asb1 = (char*)As + (w * 2 + 1) * 1024;
  char* bsb0 = (char*)Bs + (w * 2) * 1024;
  char* bsb1 = (char*)Bs + (w * 2 + 1) * 1024;

  f32x4 acc[4][4];
#pragma unroll
  for (int i = 0; i < 4; i++)
#pragma unroll
    for (int j = 0; j < 4; j++) acc[i][j] = (f32x4){0.f, 0.f, 0.f, 0.f};

  int q = lane >> 4, m16 = lane & 15;
  for (int k0 = 0; k0 < K; k0 += 32) {
    gl_lds16(A0 + k0, asb0);
    gl_lds16(A1 + k0, asb1);
    gl_lds16(B0 + k0, bsb0);
    gl_lds16(B1 + k0, bsb1);
    asm volatile("s_waitcnt vmcnt(0)" ::: "memory");
    __syncthreads();
    bf16x8 af[4], bfv[4];
#pragma unroll
    for (int f = 0; f < 4; f++)
      af[f] = *(const bf16x8*)&As[(wr * 64 + f * 16 + m16) * 32 + q * 8];
#pragma unroll
    for (int f = 0; f < 4; f++)
      bfv[f] = *(const bf16x8*)&Bs[(wc * 64 + f * 16 + m16) * 32 + q * 8];
#pragma unroll
    for (int fa = 0; fa < 4; fa++)
#pragma unroll
      for (int fb = 0; fb < 4; fb++)
        acc[fa][fb] = __builtin_amdgcn_mfma_f32_16x16x32_bf16(af[fa], bfv[fb], acc[fa][fb], 0, 0, 0);
    __syncthreads();
  }

#pragma unroll
  for (int fa = 0; fa < 4; fa++) {
#pragma unroll
    for (int fb = 0; fb < 4; fb++) {
#pragma unroll
      for (int rr = 0; rr < 4; rr++) {
        int gm = m0 + wr * 64 + fa * 16 + q * 4 + rr;
        int gn = n0 + wc * 64 + fb * 16 + m16;
        if (gn < N) {
          float v = acc[fa][fb][rr];
          if (BF16_OUT) {
            ((unsigned short*)Cout)[(size_t)gm * N + gn] = f2bf(v);
          } else {
            float o = v;
            if (RESID) o += resid[(size_t)gm * N + gn];
            ((float*)Cout)[(size_t)gm * N + gn] = o;
          }
        }
      }
    }
  }
}

// ---------------- parallel activations -> act stream (f32) ----------------
__global__ __launch_bounds__(256) void act_kernel(const unsigned short* __restrict__ qkvb,
                                                  float* __restrict__ act) {
  int gw = blockIdx.x * 4 + (threadIdx.x >> 6);
  int l = threadIdx.x & 63;
  int m = gw >> 3, hh = gw & 7;
  int t = m >> 3, b = m & 7;
  const unsigned short* src = qkvb + (size_t)m * PROJ + hh * SEG;
  float fq = bf2f(src[l]);
  float fk = bf2f(src[64 + l]);
  float fv = bf2f(src[128 + l]);
  float fr = bf2f(src[192 + l]);
  float frv = bf2f(src[256 + l]);
  float mq = fq, mk = fk, mr = fr;
#pragma unroll
  for (int o = 32; o; o >>= 1) {
    mq = fmaxf(mq, __shfl_xor(mq, o));
    mk = fmaxf(mk, __shfl_xor(mk, o));
    mr = fmaxf(mr, __shfl_xor(mr, o));
  }
  float eq = __expf(fq - mq), ek = __expf(fk - mk), er = __expf(fr - mr);
  float sq = eq, sk = ek, sr = er;
#pragma unroll
  for (int o = 32; o; o >>= 1) {
    sq += __shfl_xor(sq, o);
    sk += __shfl_xor(sk, o);
    sr += __shfl_xor(sr, o);
  }
  int bh = b * 8 + hh;
  float* dst = act + ((size_t)bh * S_LEN + t) * AST;
  dst[l] = eq * __builtin_amdgcn_rcpf(sq);
  dst[64 + l] = ek * __builtin_amdgcn_rcpf(sk);
  dst[128 + l] = er * __builtin_amdgcn_rcpf(sr);
  dst[192 + l] = fv;
  dst[256 + l] = frv;
  if (l < 2) {
    float xv = bf2f(src[320 + l]);
    dst[320 + l] = __builtin_amdgcn_rcpf(1.f + __expf(-xv));
  }
}

// ---------------- scan: W-scan and R-scan on SEPARATE CUs (private LDS pipes) ----------------
// Grid = 128 one-wave blocks. Blocks 0..63: producers (delta-rule W-scan, bh = bid),
// blocks 64..127: consumers (recurrent R-scan, bh = bid-64). Each block stages act into
// its OWN LDS (duplicate fetch; per-CU ds_read load halves vs the 2-waves-1-CU layout,
// which was the measured wall: 48 b128/step/wave at 96 VGPR forces kk re-read).
// z handoff via full-size global buffer zg (8 MB, write-once -> no reuse, no stale lines,
// no back-pressure: producers NEVER wait => deadlock-impossible). Per-chunk flags with
// agent-scope release/acquire atomics (cross-XCD safe per Guideline 16); flags cleared
// by ln_kernel earlier in the stream. Math bodies byte-identical to the verified R4 scan.
__global__ __launch_bounds__(64, 1) void scan_kernel(const float* __restrict__ act,
                                                     unsigned short* __restrict__ hs,
                                                     float* __restrict__ zg,
                                                     int* __restrict__ flags) {
  int bid = blockIdx.x;
  int role = bid >> 6;
  int bh = bid & 63;
  int b = bh >> 3, hh = bh & 7;
  int l = threadIdx.x;

  __shared__ __align__(16) float stage[2][CHUNK * AST];
  __shared__ __align__(16) float ehb[64];

  const char* abase = (const char*)(act + (size_t)bh * S_LEN * AST);
  float* zb = zg + (size_t)bh * S_LEN * 64;

  // stage chunk 0 into slot 0; full drain (also clean baseline for vmcnt accounting)
#pragma unroll
  for (int i = 0; i < 11; i++)
    gl_lds16(abase + (size_t)i * 1024 + l * 16, (char*)&stage[0][0] + i * 1024);
  asm volatile("s_waitcnt vmcnt(0)" ::: "memory");

  f32x4 M[16];
#pragma unroll
  for (int j = 0; j < 16; j++) M[j] = (f32x4){0.f, 0.f, 0.f, 0.f};
  const f32x4 z4 = {0.f, 0.f, 0.f, 0.f};

  if (role == 0) {
    // ================= producer: W-scan =================
    for (int c = 0; c < NCH; c++) {
      // staging of chunk c is the oldest vmem; newer = 8 z-stores of chunk c-1
      asm volatile("s_waitcnt vmcnt(8)" ::: "memory");
      if (c + 1 < NCH) {
        const char* nb = abase + (size_t)(c + 1) * CB;
        char* sb = (char*)&stage[(c + 1) & 1][0];
        asm volatile("" ::: "memory");
#pragma unroll
        for (int i = 0; i < 11; i++)
          gl_lds16(nb + (size_t)i * 1024 + l * 16, sb + i * 1024);
        asm volatile("" ::: "memory");
      }
      const float* cb = &stage[c & 1][0];
#pragma unroll
      for (int s = 0; s < CHUNK; s++) {
        const float* stf = cb + s * AST;
        const f32x4* st4 = (const f32x4*)stf;
        // ---- vold = W.k; fused W += coef*k, z = W.q ----
        float cv = stf[192 + l];
        f32x4 kk[16];
#pragma unroll
        for (int j = 0; j < 16; j++) kk[j] = st4[16 + j];  // k
        f32x4 a0 = z4, a1 = z4, a2 = z4, a3 = z4;
#pragma unroll
        for (int j = 0; j < 16; j += 4) {
          a0 += M[j] * kk[j];
          a1 += M[j + 1] * kk[j + 1];
          a2 += M[j + 2] * kk[j + 2];
          a3 += M[j + 3] * kk[j + 3];
        }
        f32x4 vo = (a0 + a1) + (a2 + a3);
        float vold = (vo.x + vo.y) + (vo.z + vo.w);
        float bt = stf[320];
        float coef = bt * (cv - vold);
        f32x4 c4 = {coef, coef, coef, coef};
        a0 = a1 = a2 = a3 = z4;
#pragma unroll
        for (int j = 0; j < 16; j += 4) {
          M[j] += c4 * kk[j];         a0 += M[j] * st4[j];
          M[j + 1] += c4 * kk[j + 1]; a1 += M[j + 1] * st4[j + 1];
          M[j + 2] += c4 * kk[j + 2]; a2 += M[j + 2] * st4[j + 2];
          M[j + 3] += c4 * kk[j + 3]; a3 += M[j + 3] * st4[j + 3];
        }
        vo = (a0 + a1) + (a2 + a3);
        zb[(size_t)(c * CHUNK + s) * 64 + l] = (vo.x + vo.y) + (vo.z + vo.w);
      }
      // drain z stores (and any remaining staging) before publishing the chunk
      asm volatile("s_waitcnt vmcnt(0)" ::: "memory");
      if (l == 0)
        __hip_atomic_store(&flags[bh], c + 1, __ATOMIC_RELEASE, __HIP_MEMORY_SCOPE_AGENT);
    }
  } else {
    // ================= consumer: R-scan =================
    ehb[l] = 1.f;  // softmax(h0=0) numerators -> uniform (own wave; DS-ordered)
    unsigned short* hdst = hs + (size_t)b * 512 + hh * 64 + l;
    for (int c = 0; c < NCH; c++) {
      // staging of chunk c oldest; newer = 8 z-loads + 8 h-stores of chunk c-1
      asm volatile("s_waitcnt vmcnt(16)" ::: "memory");
      while (__hip_atomic_load(&flags[bh], __ATOMIC_ACQUIRE, __HIP_MEMORY_SCOPE_AGENT) < c + 1)
        __builtin_amdgcn_s_sleep(8);
      if (c + 1 < NCH) {
        const char* nb = abase + (size_t)(c + 1) * CB;
        char* sb = (char*)&stage[(c + 1) & 1][0];
        asm volatile("" ::: "memory");
#pragma unroll
        for (int i = 0; i < 11; i++)
          gl_lds16(nb + (size_t)i * 1024 + l * 16, sb + i * 1024);
        asm volatile("" ::: "memory");
      }
      // z for the whole chunk (issued after acquire; latency hides under compute)
      float zv[CHUNK];
#pragma unroll
      for (int s = 0; s < CHUNK; s++) zv[s] = zb[(size_t)(c * CHUNK + s) * 64 + l];
      const float* cb = &stage[c & 1][0];
#pragma unroll
      for (int s = 0; s < CHUNK; s++) {
        const float* stf = cb + s * AST;
        const f32x4* st4 = (const f32x4*)stf;
        // ---- rvold = R.rk; fused R += rcoef*rk, hp = R.eh, sm = sum(eh) ----
        float cv = stf[256 + l];
        f32x4 kk[16];
#pragma unroll
        for (int j = 0; j < 16; j++) kk[j] = st4[32 + j];  // rk
        f32x4 a0 = z4, a1 = z4, a2 = z4, a3 = z4;
#pragma unroll
        for (int j = 0; j < 16; j += 4) {
          a0 += M[j] * kk[j];
          a1 += M[j + 1] * kk[j + 1];
          a2 += M[j + 2] * kk[j + 2];
          a3 += M[j + 3] * kk[j + 3];
        }
        f32x4 vo = (a0 + a1) + (a2 + a3);
        float rvold = (vo.x + vo.y) + (vo.z + vo.w);
        float rb = stf[321];
        float rcoef = rb * (cv - rvold);
        f32x4 c4 = {rcoef, rcoef, rcoef, rcoef};
        const f32x4* e4 = (const f32x4*)ehb;
        f32x4 s0 = z4, s1 = z4, s2v = z4, s3 = z4;
        a0 = a1 = a2 = a3 = z4;
#pragma unroll
        for (int j = 0; j < 16; j += 4) {
          f32x4 e0 = e4[j], e1 = e4[j + 1], e2 = e4[j + 2], e3 = e4[j + 3];
          M[j] += c4 * kk[j];         a0 += M[j] * e0;       s0 += e0;
          M[j + 1] += c4 * kk[j + 1]; a1 += M[j + 1] * e1;   s1 += e1;
          M[j + 2] += c4 * kk[j + 2]; a2 += M[j + 2] * e2;   s2v += e2;
          M[j + 3] += c4 * kk[j + 3]; a3 += M[j + 3] * e3;   s3 += e3;
        }
        f32x4 ho = (a0 + a1) + (a2 + a3);
        f32x4 so = (s0 + s1) + (s2v + s3);
        float hp = (ho.x + ho.y) + (ho.z + ho.w);
        float sm = (so.x + so.y) + (so.z + so.w);
        float h = zv[s] + hp * __builtin_amdgcn_rcpf(sm);
        hdst[(size_t)(c * CHUNK + s) * (BSZ * 512)] = f2bf(h);
        // shift-invariant: exp(h-20) keeps qh = eh/sum exact, guards overflow.
        // same-wave DS ordering makes it visible to next step's e4 reads.
        ehb[l] = __expf(h - 20.f);
      }
    }
  }
}

extern "C" void kernel_launch(void* const* d_in, const int* in_sizes, int n_in,
                              void* d_out, int out_size, void* d_ws, size_t ws_size,
                              hipStream_t stream) {
  const float* x = (const float*)d_in[0];
  const float* W_slow = (const float*)d_in[1];
  const float* W_out = (const float*)d_in[2];
  const float* gamma = (const float*)d_in[3];
  const float* beta = (const float*)d_in[4];

  char* ws = (char*)d_ws;
  size_t off = 0;
  unsigned short* normed = (unsigned short*)(ws + off); off += (size_t)4096 * 512 * 2;
  unsigned short* Wslow_b = (unsigned short*)(ws + off); off += (size_t)PROJ * 512 * 2;
  unsigned short* Wout_b = (unsigned short*)(ws + off); off += (size_t)512 * 512 * 2;
  unsigned short* qkvb = (unsigned short*)(ws + off); off += (size_t)4096 * PROJ * 2;
  float* act = (float*)(ws + off); off += (size_t)64 * S_LEN * AST * 4;
  float* zg = (float*)(ws + off); off += (size_t)64 * S_LEN * 64 * 4;
  int* flags = (int*)(ws + off); off += 256;
  unsigned short* hsb = normed;  // normed is dead after gemm1; reuse for hs

  hipLaunchKernelGGL(ln_kernel, dim3(1024), dim3(256), 0, stream, x, gamma, beta, normed, flags);
  hipLaunchKernelGGL(cast_kernel, dim3(512), dim3(256), 0, stream, W_slow, Wslow_b, PROJ * 512);
  hipLaunchKernelGGL(cast_kernel, dim3(256), dim3(256), 0, stream, W_out, Wout_b, 512 * 512);
  hipLaunchKernelGGL((gemm128<1, 0>), dim3((PROJ + 127) / 128, 4096 / 128), dim3(256), 0, stream,
                     normed, Wslow_b, (void*)qkvb, (const float*)nullptr, 4096, PROJ, 512);
  hipLaunchKernelGGL(act_kernel, dim3(8192), dim3(256), 0, stream, qkvb, act);
  hipLaunchKernelGGL(scan_kernel, dim3(128), dim3(64), 0, stream, act, hsb, zg, flags);
  hipLaunchKernelGGL((gemm128<0, 1>), dim3(512 / 128, 4096 / 128), dim3(256), 0, stream,
                     hsb, Wout_b, d_out, x, 4096, 512, 512);
}